// Round 4
// baseline (1194.573 us; speedup 1.0000x reference)
//
#include <hip/hip_runtime.h>
#include <math.h>

// Encoder: 3x (gather conv + linear + ELU) then per-graph FC.
// R3: kill the CSR scatter (190MB write-amp, 160us). Bucket edges by dst>>8
// into packed 8B records {src:16|dstlo:8, w:f32}; convs are fused
// bucket-kernels accumulating in LDS (ds_add_f32), then linear+ELU in-LDS.

#define NODES   65536
#define NGRAPH  16
#define EDGES   2097152
#define FIN     16
#define HID     32
#define KDIM    131072          // 4096*32 per-graph flattened
#define FCH     256
#define LATENT  64
#define FCB     512             // fc1 split-K blocks
#define KSLICE  (KDIM / FCB)    // 256
#define NBUCK   256
#define BNODES  256             // nodes per bucket (dst>>8)

__device__ __forceinline__ float elu_f(float v) { return v > 0.0f ? v : expf(v) - 1.0f; }

// ---------------- bucket build ----------------

__global__ void zero_small_kernel(int* __restrict__ p) {
  p[threadIdx.x] = 0;   // 1 block x 256: bucket counters
}

// 256 blocks x 1024 threads, 8 edges/thread: LDS-preaggregated bucket histogram
__global__ __launch_bounds__(1024) void bucket_hist_kernel(const int* __restrict__ ei,
                                                           int* __restrict__ bcnt) {
  __shared__ int h[NBUCK];
  if (threadIdx.x < NBUCK) h[threadIdx.x] = 0;
  __syncthreads();
  int base = blockIdx.x * 8192 + threadIdx.x;
#pragma unroll
  for (int i = 0; i < 8; ++i) {
    int dst = ei[EDGES + base + i * 1024];
    atomicAdd(&h[dst >> 8], 1);
  }
  __syncthreads();
  if (threadIdx.x < NBUCK && h[threadIdx.x] > 0) atomicAdd(&bcnt[threadIdx.x], h[threadIdx.x]);
}

// 1 block x 256: exclusive scan of bucket counts -> boff[257], gcur[256]
__global__ void bucket_scan_kernel(const int* __restrict__ bcnt, int* __restrict__ boff,
                                   int* __restrict__ gcur) {
  __shared__ int s[NBUCK];
  int t = threadIdx.x;
  int v = bcnt[t];
  s[t] = v;
  __syncthreads();
  for (int off = 1; off < NBUCK; off <<= 1) {
    int u = (t >= off) ? s[t - off] : 0;
    __syncthreads();
    s[t] += u;
    __syncthreads();
  }
  int excl = s[t] - v;
  boff[t] = excl;
  gcur[t] = excl;
  if (t == NBUCK - 1) boff[NBUCK] = EDGES;
}

// 256 blocks x 1024 threads, 8 edges/thread. Two-pass: LDS hist -> reserve
// per-bucket run via 256 global atomics -> rank via LDS cursor -> write 8B rec.
// Active write window per block = 256 buckets x 256B -> L2-resident.
__global__ __launch_bounds__(1024) void partition_kernel(const int* __restrict__ ei,
                                                         const float* __restrict__ ew,
                                                         int* __restrict__ gcur,
                                                         uint2* __restrict__ recs) {
  __shared__ int h[NBUCK];
  __shared__ int base[NBUCK];
  __shared__ int cur[NBUCK];
  if (threadIdx.x < NBUCK) { h[threadIdx.x] = 0; cur[threadIdx.x] = 0; }
  __syncthreads();
  int e0 = blockIdx.x * 8192 + threadIdx.x;
  int src[8], dst[8];
  float w[8];
#pragma unroll
  for (int i = 0; i < 8; ++i) {
    int e = e0 + i * 1024;
    src[i] = ei[e];
    dst[i] = ei[EDGES + e];
    w[i] = ew[e];
    atomicAdd(&h[dst[i] >> 8], 1);
  }
  __syncthreads();
  if (threadIdx.x < NBUCK && h[threadIdx.x] > 0)
    base[threadIdx.x] = atomicAdd(&gcur[threadIdx.x], h[threadIdx.x]);
  __syncthreads();
#pragma unroll
  for (int i = 0; i < 8; ++i) {
    int b = dst[i] >> 8;
    int r = atomicAdd(&cur[b], 1);
    uint2 rec;
    rec.x = (unsigned)src[i] | ((unsigned)(dst[i] & 255) << 16);
    rec.y = __float_as_uint(w[i]);
    recs[base[b] + r] = rec;
  }
}

// ---------------- fused conv: gather -> LDS agg -> linear+ELU ----------------
// One block per bucket. LPE = IN/4 lanes cooperate per edge (float4 each).
// agg stride IN+1 (odd) => conflict-free LDS banks in both phases.
template <int IN>
__global__ __launch_bounds__(1024) void conv_kernel(const float* __restrict__ hin,
                                                    const uint2* __restrict__ recs,
                                                    const int* __restrict__ boff,
                                                    const float* __restrict__ W,
                                                    const float* __restrict__ bias,
                                                    float* __restrict__ hout) {
  constexpr int STRIDE = IN + 1;
  constexpr int LPE = IN / 4;
  __shared__ float agg[BNODES * STRIDE];
  __shared__ float sW[IN * HID];
  __shared__ float sb[HID];
  const int tid = threadIdx.x;
  for (int i = tid; i < BNODES * STRIDE; i += 1024) agg[i] = 0.f;
  for (int i = tid; i < IN * HID; i += 1024) sW[i] = W[i];
  if (tid < HID) sb[tid] = bias[tid];
  __syncthreads();

  const int b = blockIdx.x;
  const int jb = boff[b], je = boff[b + 1];
  const int q = tid % LPE;
  const int eslot = tid / LPE;
  const int estep = 1024 / LPE;
  for (int e = jb + eslot; e < je; e += estep) {
    uint2 rec = recs[e];
    int src = rec.x & 0xFFFF;
    int dl = (rec.x >> 16) & 0xFF;
    float wv = __uint_as_float(rec.y);
    float4 hv = *reinterpret_cast<const float4*>(hin + (size_t)src * IN + q * 4);
    float* a = &agg[dl * STRIDE + q * 4];
    atomicAdd(a + 0, hv.x * wv);   // ds_add_f32 on LDS
    atomicAdd(a + 1, hv.y * wv);
    atomicAdd(a + 2, hv.z * wv);
    atomicAdd(a + 3, hv.w * wv);
  }
  __syncthreads();

  // linear: 4 threads per node, 8 out channels each
  const int node = tid >> 2;
  const int c0 = (tid & 3) * 8;
  float o[8];
#pragma unroll
  for (int j = 0; j < 8; ++j) o[j] = sb[c0 + j];
#pragma unroll
  for (int i = 0; i < IN; ++i) {
    float ai = agg[node * STRIDE + i];
#pragma unroll
    for (int j = 0; j < 8; ++j) o[j] += ai * sW[i * HID + c0 + j];
  }
  float* dst = hout + ((size_t)b * BNODES + node) * HID + c0;
  float4 v0 = make_float4(elu_f(o[0]), elu_f(o[1]), elu_f(o[2]), elu_f(o[3]));
  float4 v1 = make_float4(elu_f(o[4]), elu_f(o[5]), elu_f(o[6]), elu_f(o[7]));
  *reinterpret_cast<float4*>(dst) = v0;
  *reinterpret_cast<float4*>(dst + 4) = v1;
}

// ---------------- FC1 split-K ----------------
__global__ void fc1_partial_kernel(const float* __restrict__ h, const float* __restrict__ W,
                                   float* __restrict__ part) {
  __shared__ float red[NGRAPH * FCH];      // 16 KB
  const int tid = threadIdx.x;
  const int lane = tid & 63;
  const int wv = tid >> 6;
  const int k0 = blockIdx.x * KSLICE;
  float4 acc[NGRAPH];
#pragma unroll
  for (int g = 0; g < NGRAPH; ++g) acc[g] = make_float4(0.f, 0.f, 0.f, 0.f);
  for (int kk = wv; kk < KSLICE; kk += 4) {
    const int k = k0 + kk;
    const float4 wr = *reinterpret_cast<const float4*>(W + (size_t)k * FCH + lane * 4);
#pragma unroll
    for (int g = 0; g < NGRAPH; ++g) {
      const float hv = h[(size_t)g * KDIM + k];  // wave-uniform -> 1 request
      acc[g].x += wr.x * hv; acc[g].y += wr.y * hv;
      acc[g].z += wr.z * hv; acc[g].w += wr.w * hv;
    }
  }
  for (int i = tid; i < NGRAPH * FCH; i += blockDim.x) red[i] = 0.f;
  __syncthreads();
#pragma unroll
  for (int g = 0; g < NGRAPH; ++g) {
    atomicAdd(&red[g * FCH + lane * 4 + 0], acc[g].x);
    atomicAdd(&red[g * FCH + lane * 4 + 1], acc[g].y);
    atomicAdd(&red[g * FCH + lane * 4 + 2], acc[g].z);
    atomicAdd(&red[g * FCH + lane * 4 + 3], acc[g].w);
  }
  __syncthreads();
  float* dst = part + (size_t)blockIdx.x * (NGRAPH * FCH);
  for (int i = tid; i < NGRAPH * FCH; i += blockDim.x) dst[i] = red[i];
}

__global__ void fc1_reduce_kernel(const float* __restrict__ part, const float* __restrict__ bfc1,
                                  float* __restrict__ act) {
  __shared__ float red[4][64];
  const int g = blockIdx.x >> 2;
  const int c0 = (blockIdx.x & 3) * 64;
  const int lane = threadIdx.x & 63;
  const int wv = threadIdx.x >> 6;
  const int c = c0 + lane;
  float s = 0.f;
#pragma unroll 8
  for (int b = wv; b < FCB; b += 4) s += part[(size_t)b * (NGRAPH * FCH) + g * FCH + c];
  red[wv][lane] = s;
  __syncthreads();
  if (wv == 0) {
    float v = red[0][lane] + red[1][lane] + red[2][lane] + red[3][lane];
    act[g * FCH + c] = elu_f(v + bfc1[c]);
  }
}

__global__ void fc2_kernel(const float* __restrict__ act, const float* __restrict__ Wfc2,
                           const float* __restrict__ bfc2, float* __restrict__ out) {
  const int g = blockIdx.x;
  const int c = threadIdx.x;
  float o = bfc2[c];
#pragma unroll 8
  for (int i = 0; i < FCH; ++i) o += act[g * FCH + i] * Wfc2[i * LATENT + c];
  out[g * LATENT + c] = o;
}

extern "C" void kernel_launch(void* const* d_in, const int* in_sizes, int n_in,
                              void* d_out, int out_size, void* d_ws, size_t ws_size,
                              hipStream_t stream) {
  const float* x    = (const float*)d_in[0];
  const float* ea   = (const float*)d_in[1];
  const float* W1   = (const float*)d_in[2];
  const float* b1   = (const float*)d_in[3];
  const float* W2   = (const float*)d_in[4];
  const float* b2   = (const float*)d_in[5];
  const float* W3   = (const float*)d_in[6];
  const float* b3   = (const float*)d_in[7];
  const float* Wfc1 = (const float*)d_in[8];
  const float* bfc1 = (const float*)d_in[9];
  const float* Wfc2 = (const float*)d_in[10];
  const float* bfc2 = (const float*)d_in[11];
  const int*   ei   = (const int*)d_in[12];
  float* out = (float*)d_out;

  char* w = (char*)d_ws;
  uint2* recs   = (uint2*)(w + 0);                           // 16 MB
  float* hA     = (float*)(w + (size_t)(16 << 20));          // 8 MB (h1 then h3)
  float* hB     = (float*)(w + (size_t)(24 << 20));          // 8 MB (h2 then fc partials)
  int*   bcnt   = (int*)  (w + (size_t)(32 << 20));          // 1 KB
  int*   boff   = (int*)  (w + (size_t)(32 << 20) + 4096);   // 1 KB + 4
  int*   gcur   = (int*)  (w + (size_t)(32 << 20) + 8192);   // 1 KB
  float* act    = (float*)(w + (size_t)(32 << 20) + 12288);  // 16 KB
  float* part   = hB;

  // ---- bucketed edge build ----
  zero_small_kernel<<<1, 256, 0, stream>>>(bcnt);
  bucket_hist_kernel<<<NBUCK, 1024, 0, stream>>>(ei, bcnt);
  bucket_scan_kernel<<<1, 256, 0, stream>>>(bcnt, boff, gcur);
  partition_kernel<<<NBUCK, 1024, 0, stream>>>(ei, ea, gcur, recs);

  // ---- fused convs ----
  conv_kernel<16><<<NBUCK, 1024, 0, stream>>>(x,  recs, boff, W1, b1, hA);
  conv_kernel<32><<<NBUCK, 1024, 0, stream>>>(hA, recs, boff, W2, b2, hB);
  conv_kernel<32><<<NBUCK, 1024, 0, stream>>>(hB, recs, boff, W3, b3, hA);

  // ---- FC head ----
  fc1_partial_kernel<<<FCB, 256, 0, stream>>>(hA, Wfc1, part);
  fc1_reduce_kernel<<<64, 256, 0, stream>>>(part, bfc1, act);
  fc2_kernel<<<NGRAPH, 64, 0, stream>>>(act, Wfc2, bfc2, out);
}